// Round 1
// baseline (1190.881 us; speedup 1.0000x reference)
//
#include <hip/hip_runtime.h>
#include <hip/hip_bf16.h>

// ---------------------------------------------------------------------------
// YOLOv3 post-processing for MI355X.
// Inputs (fp32): feats0 [8,255,19,19], feats1 [8,255,38,38], feats2 [8,255,76,76],
//                anchors [9,2], image_shape [2], ori_shape [8,2]
// Output (flat fp32): dets [8,100,5] ++ det_cls [8,100] ++ det_valid [8,100]
// ---------------------------------------------------------------------------

#define BATCH 8
#define NC 80
#define G0 19
#define G1 38
#define G2 76
#define C0 (G0*G0)          // 361
#define C1 (G1*G1)          // 1444
#define C2 (G2*G2)          // 5776
#define CELLS (C0+C1+C2)    // 7581
#define OFF_L0 0
#define OFF_L1 (C0*3)       // 1083
#define OFF_L2 (OFF_L1 + C1*3) // 5415
#define NBOX (CELLS*3)      // 22743
#define CAP 4096
#define TK 100
#define SCORE_TH 0.5f
#define NMS_TH 0.3f

// workspace layout (bytes, all 8-aligned)
#define OFF_CAND   ((size_t)0)                                  // u64[640*CAP]   = 20,971,520
#define OFF_BOXES  ((size_t)20971520)                           // f32[8*NBOX*4]  =  2,911,104
#define OFF_CSCORE ((size_t)23882624)                           // f32[8*8000]    =    256,000
#define OFF_CBOX   ((size_t)24138624)                           // f32[8*8000*4]  =  1,024,000
#define OFF_STAGE  ((size_t)25162624)                           // u64[8*1000]    =     64,000
#define OFF_CNT    ((size_t)25226624)                           // u32[640]       =      2,560

__device__ __forceinline__ float sigmoidf_(float x) {
    return 1.0f / (1.0f + expf(-x));
}

// descending bitonic sort of M (pow2) u64 keys in LDS
__device__ __forceinline__ void bitonic_desc(unsigned long long* s, unsigned M,
                                             unsigned tid, unsigned nthr) {
    for (unsigned k = 2; k <= M; k <<= 1) {
        for (unsigned j = k >> 1; j > 0; j >>= 1) {
            for (unsigned t = tid; t < M; t += nthr) {
                unsigned p = t ^ j;
                if (p > t) {
                    unsigned long long a = s[t], b = s[p];
                    bool desc = ((t & k) == 0);
                    if (desc ? (a < b) : (a > b)) { s[t] = b; s[p] = a; }
                }
            }
            __syncthreads();
        }
    }
}

// ---------------------------------------------------------------------------
// Kernel 1: decode boxes + scatter (score,idx) candidates with score >= 0.5
// one thread per (image, grid cell); loops 3 anchors x 80 classes
// ---------------------------------------------------------------------------
__global__ __launch_bounds__(256) void decode_kernel(
        const float* __restrict__ f0, const float* __restrict__ f1,
        const float* __restrict__ f2, const float* __restrict__ anchors,
        const float* __restrict__ image_shape,
        float* __restrict__ boxes, unsigned* __restrict__ cnt,
        unsigned long long* __restrict__ cand) {
    int t = blockIdx.x * blockDim.x + threadIdx.x;
    if (t >= BATCH * CELLS) return;
    int b = t / CELLS;
    int cell = t - b * CELLS;

    int layer, g, cl, off;
    const float* f;
    if (cell < C0)            { layer = 0; g = G0; cl = cell;            off = OFF_L0; f = f0 + (size_t)b * 255 * C0; }
    else if (cell < C0 + C1)  { layer = 1; g = G1; cl = cell - C0;       off = OFF_L1; f = f1 + (size_t)b * 255 * C1; }
    else                      { layer = 2; g = G2; cl = cell - C0 - C1;  off = OFF_L2; f = f2 + (size_t)b * 255 * C2; }
    int S = g * g;
    int y = cl / g;
    int x = cl - y * g;

    const float in0 = (float)(G0 * 32);   // input_shape = [608, 608]
    const float in1 = (float)(G0 * 32);
    float img0 = image_shape[0], img1 = image_shape[1];
    float mr   = fminf(in0 / img0, in1 / img1);
    float new0 = rintf(img0 * mr), new1 = rintf(img1 * mr);
    float ofs0 = (in0 - new0) * 0.5f / in0;
    float ofs1 = (in1 - new1) * 0.5f / in1;
    float scl0 = in0 / new0, scl1 = in1 / new1;

    for (int a = 0; a < 3; ++a) {
        const float* fa = f + (size_t)(a * 85) * S + cl;
        float tx = fa[0];
        float ty = fa[(size_t)S];
        float tw = fa[(size_t)2 * S];
        float th = fa[(size_t)3 * S];
        float tc = fa[(size_t)4 * S];

        int am = (2 - layer) * 3 + a;            // ANCHOR_MASK
        float aw = anchors[am * 2 + 0];
        float ah = anchors[am * 2 + 1];

        // box_xy comp0=(sig(tx)+x)/gh, comp1=(sig(ty)+y)/gw ; box_yx = reversed
        float bx = (sigmoidf_(tx) + (float)x) / (float)g;
        float by = (sigmoidf_(ty) + (float)y) / (float)g;
        // box_wh comp0=exp(tw)*aw/in0, comp1=exp(th)*ah/in1 ; box_hw = reversed
        float bw = expf(tw) * aw / in0;
        float bh = expf(th) * ah / in1;

        float yy = (by - ofs0) * scl0;
        float xx = (bx - ofs1) * scl1;
        float hh = bh * scl0;
        float ww = bw * scl1;

        float b0 = (yy - hh * 0.5f) * img0;   // ymin
        float b1 = (xx - ww * 0.5f) * img1;   // xmin
        float b2 = (yy + hh * 0.5f) * img0;   // ymax
        float b3 = (xx + ww * 0.5f) * img1;   // xmax

        int gidx = off + cl * 3 + a;
        float* bp = boxes + ((size_t)b * NBOX + gidx) * 4;
        bp[0] = b0; bp[1] = b1; bp[2] = b2; bp[3] = b3;

        float conf = sigmoidf_(tc);
        for (int c = 0; c < NC; ++c) {
            float p = sigmoidf_(fa[(size_t)(5 + c) * S]);
            float s = conf * p;
            if (s >= SCORE_TH) {
                int bc = b * NC + c;
                unsigned slot = atomicAdd(&cnt[bc], 1u);
                if (slot < CAP) {
                    unsigned long long key =
                        ((unsigned long long)__float_as_uint(s) << 32) |
                        (unsigned)(~(unsigned)gidx);
                    cand[(size_t)bc * CAP + slot] = key;
                }
            }
        }
    }
}

// ---------------------------------------------------------------------------
// Kernel 2: per-(image,class) sort candidates desc, top-100, sequential NMS
// one block per (b,c); writes cand scores (-1 if not kept) + boxes
// ---------------------------------------------------------------------------
__global__ __launch_bounds__(256) void nms_kernel(
        const unsigned* __restrict__ cnt,
        const unsigned long long* __restrict__ cand,
        const float* __restrict__ boxes,
        float* __restrict__ cscore, float* __restrict__ cbox) {
    __shared__ unsigned long long s[CAP];
    __shared__ float bx[TK][4];
    __shared__ float sc[TK];
    __shared__ int keep[TK];

    int bc = blockIdx.x;
    int b = bc / NC;
    int c = bc - b * NC;
    unsigned tid = threadIdx.x;

    unsigned n = cnt[bc];
    if (n > CAP) n = CAP;
    unsigned M = 128;
    while (M < n) M <<= 1;

    const unsigned long long* cp = cand + (size_t)bc * CAP;
    for (unsigned t = tid; t < M; t += 256) s[t] = (t < n) ? cp[t] : 0ULL;
    __syncthreads();

    bitonic_desc(s, M, tid, 256);

    int nv = (int)n < TK ? (int)n : TK;
    if (tid < TK) {
        if ((int)tid < nv) {
            unsigned long long key = s[tid];
            sc[tid] = __uint_as_float((unsigned)(key >> 32));
            unsigned gidx = ~(unsigned)(key & 0xFFFFFFFFu);
            const float* bp = boxes + ((size_t)b * NBOX + gidx) * 4;
            bx[tid][0] = bp[0]; bx[tid][1] = bp[1];
            bx[tid][2] = bp[2]; bx[tid][3] = bp[3];
            keep[tid] = 1;
        } else {
            sc[tid] = -1.0f;
            bx[tid][0] = bx[tid][1] = bx[tid][2] = bx[tid][3] = 0.0f;
            keep[tid] = 0;
        }
    }
    __syncthreads();

    // sequential NMS: iteration i suppresses j>i with IoU>TH if keep[i]
    for (int i = 0; i < nv - 1; ++i) {
        bool ki = (keep[i] != 0);
        if (ki && (int)tid > i && (int)tid < nv && keep[tid]) {
            float a0 = bx[i][0], a1 = bx[i][1], a2 = bx[i][2], a3 = bx[i][3];
            float c0 = bx[tid][0], c1 = bx[tid][1], c2 = bx[tid][2], c3 = bx[tid][3];
            float areaA = fmaxf(a2 - a0, 0.0f) * fmaxf(a3 - a1, 0.0f);
            float areaC = fmaxf(c2 - c0, 0.0f) * fmaxf(c3 - c1, 0.0f);
            float tl0 = fmaxf(a0, c0), tl1 = fmaxf(a1, c1);
            float br0 = fminf(a2, c2), br1 = fminf(a3, c3);
            float w = fmaxf(br0 - tl0, 0.0f), h = fmaxf(br1 - tl1, 0.0f);
            float inter = w * h;
            float iou = inter / (areaA + areaC - inter + 1e-9f);
            if (iou > NMS_TH) keep[tid] = 0;
        }
        __syncthreads();
    }

    if (tid < TK) {
        size_t o = (size_t)b * 8000 + (size_t)c * TK + tid;
        bool k = (keep[tid] != 0);
        cscore[o] = k ? sc[tid] : -1.0f;
        float* cb = cbox + o * 4;
        cb[0] = bx[tid][0]; cb[1] = bx[tid][1];
        cb[2] = bx[tid][2]; cb[3] = bx[tid][3];
    }
}

// flip fp32 bits to a totally ordered unsigned (handles negatives)
__device__ __forceinline__ unsigned fflip(float v) {
    unsigned u = __float_as_uint(v);
    return (u & 0x80000000u) ? ~u : (u | 0x80000000u);
}
__device__ __forceinline__ float funflip(unsigned u) {
    return __uint_as_float((u & 0x80000000u) ? (u & 0x7FFFFFFFu) : ~u);
}

// ---------------------------------------------------------------------------
// Kernel 3a: per (image, chunk of 8 classes = 800 entries) -> top-100 keys
// ---------------------------------------------------------------------------
__global__ __launch_bounds__(256) void topk1_kernel(
        const float* __restrict__ cscore, unsigned long long* __restrict__ stage) {
    __shared__ unsigned long long s[1024];
    int blk = blockIdx.x;               // 0..79
    int b = blk / 10;
    int g = blk - b * 10;
    unsigned tid = threadIdx.x;
    for (unsigned t = tid; t < 1024; t += 256) {
        unsigned long long key = 0ULL;
        if (t < 800) {
            unsigned e = (unsigned)(g * 800 + t);   // flat idx within image 0..7999
            float v = cscore[(size_t)b * 8000 + e];
            key = ((unsigned long long)fflip(v) << 32) | (unsigned)(~e);
        }
        s[t] = key;
    }
    __syncthreads();
    bitonic_desc(s, 1024, tid, 256);
    if (tid < TK) stage[(size_t)b * 1000 + (size_t)g * TK + tid] = s[tid];
}

// ---------------------------------------------------------------------------
// Kernel 3b: per image -> top-100 of 1000 staged keys, rescale, write output
// ---------------------------------------------------------------------------
__global__ __launch_bounds__(256) void topk2_kernel(
        const unsigned long long* __restrict__ stage,
        const float* __restrict__ cbox,
        const float* __restrict__ image_shape,
        const float* __restrict__ ori,
        float* __restrict__ out) {
    __shared__ unsigned long long s[1024];
    int b = blockIdx.x;
    unsigned tid = threadIdx.x;
    for (unsigned t = tid; t < 1024; t += 256)
        s[t] = (t < 1000) ? stage[(size_t)b * 1000 + t] : 0ULL;
    __syncthreads();
    bitonic_desc(s, 1024, tid, 256);

    if (tid < TK) {
        unsigned long long key = s[tid];
        float v = funflip((unsigned)(key >> 32));
        unsigned e = ~(unsigned)(key & 0xFFFFFFFFu);
        bool valid = (v >= SCORE_TH);

        float w = image_shape[0], h = image_shape[1];
        float iw = ori[b * 2 + 0], ih = ori[b * 2 + 1];
        float scale = fminf(w / iw, h / ih);
        float nw = floorf(iw * scale), nh = floorf(ih * scale);
        float dx = floorf((w - nw) * 0.5f), dy = floorf((h - nh) * 0.5f);

        const float* cb = cbox + ((size_t)b * 8000 + e) * 4;
        float r0 = (cb[0] - dx) / scale;
        float r1 = (cb[1] - dy) / scale;
        float r2 = (cb[2] - dx) / scale;
        float r3 = (cb[3] - dy) / scale;

        size_t row = (size_t)b * TK + tid;
        float* dp = out + row * 5;
        dp[0] = valid ? r0 : 0.0f;
        dp[1] = valid ? r1 : 0.0f;
        dp[2] = valid ? r2 : 0.0f;
        dp[3] = valid ? r3 : 0.0f;
        dp[4] = valid ? v  : 0.0f;
        out[(size_t)BATCH * TK * 5 + row] = valid ? (float)(e / TK + 1) : 0.0f;  // cls
        out[(size_t)BATCH * TK * 6 + row] = valid ? 1.0f : 0.0f;                 // valid
    }
}

extern "C" void kernel_launch(void* const* d_in, const int* in_sizes, int n_in,
                              void* d_out, int out_size, void* d_ws, size_t ws_size,
                              hipStream_t stream) {
    const float* f0  = (const float*)d_in[0];
    const float* f1  = (const float*)d_in[1];
    const float* f2  = (const float*)d_in[2];
    const float* anc = (const float*)d_in[3];
    const float* ish = (const float*)d_in[4];
    const float* ori = (const float*)d_in[5];
    float* out = (float*)d_out;

    char* ws = (char*)d_ws;
    unsigned long long* cand  = (unsigned long long*)(ws + OFF_CAND);
    float*              boxes = (float*)(ws + OFF_BOXES);
    float*              cscr  = (float*)(ws + OFF_CSCORE);
    float*              cbox  = (float*)(ws + OFF_CBOX);
    unsigned long long* stage = (unsigned long long*)(ws + OFF_STAGE);
    unsigned*           cnt   = (unsigned*)(ws + OFF_CNT);

    hipMemsetAsync(cnt, 0, BATCH * NC * sizeof(unsigned), stream);

    int nThreads = BATCH * CELLS;
    int nBlocks = (nThreads + 255) / 256;
    decode_kernel<<<nBlocks, 256, 0, stream>>>(f0, f1, f2, anc, ish, boxes, cnt, cand);

    nms_kernel<<<BATCH * NC, 256, 0, stream>>>(cnt, cand, boxes, cscr, cbox);

    topk1_kernel<<<BATCH * 10, 256, 0, stream>>>(cscr, stage);

    topk2_kernel<<<BATCH, 256, 0, stream>>>(stage, cbox, ish, ori, out);
}

// Round 2
// 797.868 us; speedup vs baseline: 1.4926x; 1.4926x over previous
//
#include <hip/hip_runtime.h>
#include <hip/hip_bf16.h>

// ---------------------------------------------------------------------------
// YOLOv3 post-processing for MI355X.
// Inputs (fp32): feats0 [8,255,19,19], feats1 [8,255,38,38], feats2 [8,255,76,76],
//                anchors [9,2], image_shape [2], ori_shape [8,2]
// Output (flat fp32): dets [8,100,5] ++ det_cls [8,100] ++ det_valid [8,100]
// ---------------------------------------------------------------------------

#define BATCH 8
#define NC 80
#define G0 19
#define G1 38
#define G2 76
#define C0 (G0*G0)          // 361
#define C1 (G1*G1)          // 1444
#define C2 (G2*G2)          // 5776
#define CELLS (C0+C1+C2)    // 7581
#define PCELLS 7616         // CELLS padded to multiple of 64 (wave-uniform class)
#define OFF_L0 0
#define OFF_L1 (C0*3)       // 1083
#define OFF_L2 (OFF_L1 + C1*3) // 5415
#define NBOX (CELLS*3)      // 22743
#define CAP 4096
#define TK 100
#define SCORE_TH 0.5f
#define NMS_TH 0.3f

// workspace layout (bytes, all 16-aligned)
#define OFF_CAND   ((size_t)0)                                  // u64[640*CAP]   = 20,971,520
#define OFF_BOXES  ((size_t)20971520)                           // f32[8*NBOX*4]  =  2,911,104
#define OFF_CSCORE ((size_t)23882624)                           // f32[8*8000]    =    256,000
#define OFF_CBOX   ((size_t)24138624)                           // f32[8*8000*4]  =  1,024,000
#define OFF_STAGE  ((size_t)25162624)                           // u64[8*1000]    =     64,000
#define OFF_CNT    ((size_t)25226624)                           // u32[640]       =      2,560

__device__ __forceinline__ float sigmoidf_(float x) {
    return 1.0f / (1.0f + expf(-x));
}

// descending bitonic sort of M (pow2) u64 keys in LDS
__device__ __forceinline__ void bitonic_desc(unsigned long long* s, unsigned M,
                                             unsigned tid, unsigned nthr) {
    for (unsigned k = 2; k <= M; k <<= 1) {
        for (unsigned j = k >> 1; j > 0; j >>= 1) {
            for (unsigned t = tid; t < M; t += nthr) {
                unsigned p = t ^ j;
                if (p > t) {
                    unsigned long long a = s[t], b = s[p];
                    bool desc = ((t & k) == 0);
                    if (desc ? (a < b) : (a > b)) { s[t] = b; s[p] = a; }
                }
            }
            __syncthreads();
        }
    }
}

// map a combined cell index [0, CELLS) to (layer geometry)
__device__ __forceinline__ void cell_decomp(int cell, int& g, int& cl, int& off, int& layer) {
    if (cell < C0)            { layer = 0; g = G0; cl = cell;            off = OFF_L0; }
    else if (cell < C0 + C1)  { layer = 1; g = G1; cl = cell - C0;       off = OFF_L1; }
    else                      { layer = 2; g = G2; cl = cell - C0 - C1;  off = OFF_L2; }
}

// ---------------------------------------------------------------------------
// Kernel A: decode boxes. one thread per (image, cell); 3 anchors unrolled.
// ---------------------------------------------------------------------------
__global__ __launch_bounds__(256) void box_kernel(
        const float* __restrict__ f0, const float* __restrict__ f1,
        const float* __restrict__ f2, const float* __restrict__ anchors,
        const float* __restrict__ image_shape,
        float* __restrict__ boxes) {
    int t = blockIdx.x * blockDim.x + threadIdx.x;
    if (t >= BATCH * CELLS) return;
    int b = t / CELLS;
    int cell = t - b * CELLS;

    int layer, g, cl, off;
    cell_decomp(cell, g, cl, off, layer);
    const float* f;
    if (layer == 0)      f = f0 + (size_t)b * 255 * C0;
    else if (layer == 1) f = f1 + (size_t)b * 255 * C1;
    else                 f = f2 + (size_t)b * 255 * C2;
    int S = g * g;
    int y = cl / g;
    int x = cl - y * g;

    const float in0 = (float)(G0 * 32);   // 608
    const float in1 = (float)(G0 * 32);
    float img0 = image_shape[0], img1 = image_shape[1];
    float mr   = fminf(in0 / img0, in1 / img1);
    float new0 = rintf(img0 * mr), new1 = rintf(img1 * mr);
    float ofs0 = (in0 - new0) * 0.5f / in0;
    float ofs1 = (in1 - new1) * 0.5f / in1;
    float scl0 = in0 / new0, scl1 = in1 / new1;

    #pragma unroll
    for (int a = 0; a < 3; ++a) {
        const float* fa = f + (size_t)(a * 85) * S + cl;
        float tx = fa[0];
        float ty = fa[(size_t)S];
        float tw = fa[(size_t)2 * S];
        float th = fa[(size_t)3 * S];

        int am = (2 - layer) * 3 + a;            // ANCHOR_MASK
        float aw = anchors[am * 2 + 0];
        float ah = anchors[am * 2 + 1];

        float bx = (sigmoidf_(tx) + (float)x) / (float)g;
        float by = (sigmoidf_(ty) + (float)y) / (float)g;
        float bw = expf(tw) * aw / in0;
        float bh = expf(th) * ah / in1;

        float yy = (by - ofs0) * scl0;
        float xx = (bx - ofs1) * scl1;
        float hh = bh * scl0;
        float ww = bw * scl1;

        float4 bb;
        bb.x = (yy - hh * 0.5f) * img0;   // ymin
        bb.y = (xx - ww * 0.5f) * img1;   // xmin
        bb.z = (yy + hh * 0.5f) * img0;   // ymax
        bb.w = (xx + ww * 0.5f) * img1;   // xmax

        int gidx = off + cl * 3 + a;
        *(float4*)(boxes + ((size_t)b * NBOX + gidx) * 4) = bb;
    }
}

// ---------------------------------------------------------------------------
// Kernel B: scores + scatter. one thread per (b, anchor, class, padded-cell).
// Every wave is uniform in (b, a, c) -> wave-aggregated atomic append.
// ---------------------------------------------------------------------------
__global__ __launch_bounds__(256) void score_kernel(
        const float* __restrict__ f0, const float* __restrict__ f1,
        const float* __restrict__ f2,
        unsigned* __restrict__ cnt,
        unsigned long long* __restrict__ cand) {
    long long tid = (long long)blockIdx.x * blockDim.x + threadIdx.x;
    int cellp = (int)(tid % PCELLS);
    int plane = (int)(tid / PCELLS);
    if (plane >= BATCH * 3 * NC) return;
    int c  = plane % NC;
    int t2 = plane / NC;
    int a  = t2 % 3;
    int b  = t2 / 3;

    bool pred = false;
    float s = 0.0f;
    int gidx = 0;
    if (cellp < CELLS) {
        int layer, g, cl, off;
        cell_decomp(cellp, g, cl, off, layer);
        const float* f;
        if (layer == 0)      f = f0 + (size_t)b * 255 * C0;
        else if (layer == 1) f = f1 + (size_t)b * 255 * C1;
        else                 f = f2 + (size_t)b * 255 * C2;
        int S = g * g;
        const float* fa = f + (size_t)(a * 85) * S + cl;
        float tc = fa[(size_t)4 * S];
        float pl = fa[(size_t)(5 + c) * S];
        s = sigmoidf_(tc) * sigmoidf_(pl);   // identical expression to validated r0
        gidx = off + cl * 3 + a;
        pred = (s >= SCORE_TH);
    }

    unsigned long long m = __ballot(pred);
    if (pred) {
        int lane = threadIdx.x & 63;
        int rank = __popcll(m & ((1ULL << lane) - 1ULL));
        int leader = __ffsll((long long)m) - 1;
        int bc = b * NC + c;                  // wave-uniform
        unsigned base = 0;
        if (lane == leader) base = atomicAdd(&cnt[bc], (unsigned)__popcll(m));
        base = (unsigned)__shfl((int)base, leader);
        unsigned slot = base + (unsigned)rank;
        if (slot < CAP) {
            unsigned long long key =
                ((unsigned long long)__float_as_uint(s) << 32) |
                (unsigned)(~(unsigned)gidx);
            cand[(size_t)bc * CAP + slot] = key;
        }
    }
}

// ---------------------------------------------------------------------------
// Kernel 2: per-(image,class) sort candidates desc, top-100, sequential NMS
// ---------------------------------------------------------------------------
__global__ __launch_bounds__(512) void nms_kernel(
        const unsigned* __restrict__ cnt,
        const unsigned long long* __restrict__ cand,
        const float* __restrict__ boxes,
        float* __restrict__ cscore, float* __restrict__ cbox) {
    __shared__ unsigned long long s[CAP];
    __shared__ float bx[TK][4];
    __shared__ float sc[TK];
    __shared__ int keep[TK];

    int bc = blockIdx.x;
    int b = bc / NC;
    int c = bc - b * NC;
    unsigned tid = threadIdx.x;

    unsigned n = cnt[bc];
    if (n > CAP) n = CAP;
    unsigned M = 128;
    while (M < n) M <<= 1;

    const unsigned long long* cp = cand + (size_t)bc * CAP;
    for (unsigned t = tid; t < M; t += 512) s[t] = (t < n) ? cp[t] : 0ULL;
    __syncthreads();

    bitonic_desc(s, M, tid, 512);

    int nv = (int)n < TK ? (int)n : TK;
    if (tid < TK) {
        if ((int)tid < nv) {
            unsigned long long key = s[tid];
            sc[tid] = __uint_as_float((unsigned)(key >> 32));
            unsigned gidx = ~(unsigned)(key & 0xFFFFFFFFu);
            const float* bp = boxes + ((size_t)b * NBOX + gidx) * 4;
            bx[tid][0] = bp[0]; bx[tid][1] = bp[1];
            bx[tid][2] = bp[2]; bx[tid][3] = bp[3];
            keep[tid] = 1;
        } else {
            sc[tid] = -1.0f;
            bx[tid][0] = bx[tid][1] = bx[tid][2] = bx[tid][3] = 0.0f;
            keep[tid] = 0;
        }
    }
    __syncthreads();

    // sequential NMS: iteration i suppresses j>i with IoU>TH if keep[i]
    for (int i = 0; i < nv - 1; ++i) {
        bool ki = (keep[i] != 0);
        if (ki && (int)tid > i && (int)tid < nv && keep[tid]) {
            float a0 = bx[i][0], a1 = bx[i][1], a2 = bx[i][2], a3 = bx[i][3];
            float c0 = bx[tid][0], c1 = bx[tid][1], c2 = bx[tid][2], c3 = bx[tid][3];
            float areaA = fmaxf(a2 - a0, 0.0f) * fmaxf(a3 - a1, 0.0f);
            float areaC = fmaxf(c2 - c0, 0.0f) * fmaxf(c3 - c1, 0.0f);
            float tl0 = fmaxf(a0, c0), tl1 = fmaxf(a1, c1);
            float br0 = fminf(a2, c2), br1 = fminf(a3, c3);
            float w = fmaxf(br0 - tl0, 0.0f), h = fmaxf(br1 - tl1, 0.0f);
            float inter = w * h;
            float iou = inter / (areaA + areaC - inter + 1e-9f);
            if (iou > NMS_TH) keep[tid] = 0;
        }
        __syncthreads();
    }

    if (tid < TK) {
        size_t o = (size_t)b * 8000 + (size_t)c * TK + tid;
        bool k = (keep[tid] != 0);
        cscore[o] = k ? sc[tid] : -1.0f;
        float* cb = cbox + o * 4;
        cb[0] = bx[tid][0]; cb[1] = bx[tid][1];
        cb[2] = bx[tid][2]; cb[3] = bx[tid][3];
    }
}

// flip fp32 bits to a totally ordered unsigned (handles negatives)
__device__ __forceinline__ unsigned fflip(float v) {
    unsigned u = __float_as_uint(v);
    return (u & 0x80000000u) ? ~u : (u | 0x80000000u);
}
__device__ __forceinline__ float funflip(unsigned u) {
    return __uint_as_float((u & 0x80000000u) ? (u & 0x7FFFFFFFu) : ~u);
}

// ---------------------------------------------------------------------------
// Kernel 3a: per (image, chunk of 8 classes = 800 entries) -> top-100 keys
// ---------------------------------------------------------------------------
__global__ __launch_bounds__(256) void topk1_kernel(
        const float* __restrict__ cscore, unsigned long long* __restrict__ stage) {
    __shared__ unsigned long long s[1024];
    int blk = blockIdx.x;               // 0..79
    int b = blk / 10;
    int g = blk - b * 10;
    unsigned tid = threadIdx.x;
    for (unsigned t = tid; t < 1024; t += 256) {
        unsigned long long key = 0ULL;
        if (t < 800) {
            unsigned e = (unsigned)(g * 800 + t);   // flat idx within image 0..7999
            float v = cscore[(size_t)b * 8000 + e];
            key = ((unsigned long long)fflip(v) << 32) | (unsigned)(~e);
        }
        s[t] = key;
    }
    __syncthreads();
    bitonic_desc(s, 1024, tid, 256);
    if (tid < TK) stage[(size_t)b * 1000 + (size_t)g * TK + tid] = s[tid];
}

// ---------------------------------------------------------------------------
// Kernel 3b: per image -> top-100 of 1000 staged keys, rescale, write output
// ---------------------------------------------------------------------------
__global__ __launch_bounds__(256) void topk2_kernel(
        const unsigned long long* __restrict__ stage,
        const float* __restrict__ cbox,
        const float* __restrict__ image_shape,
        const float* __restrict__ ori,
        float* __restrict__ out) {
    __shared__ unsigned long long s[1024];
    int b = blockIdx.x;
    unsigned tid = threadIdx.x;
    for (unsigned t = tid; t < 1024; t += 256)
        s[t] = (t < 1000) ? stage[(size_t)b * 1000 + t] : 0ULL;
    __syncthreads();
    bitonic_desc(s, 1024, tid, 256);

    if (tid < TK) {
        unsigned long long key = s[tid];
        float v = funflip((unsigned)(key >> 32));
        unsigned e = ~(unsigned)(key & 0xFFFFFFFFu);
        bool valid = (v >= SCORE_TH);

        float w = image_shape[0], h = image_shape[1];
        float iw = ori[b * 2 + 0], ih = ori[b * 2 + 1];
        float scale = fminf(w / iw, h / ih);
        float nw = floorf(iw * scale), nh = floorf(ih * scale);
        float dx = floorf((w - nw) * 0.5f), dy = floorf((h - nh) * 0.5f);

        const float* cb = cbox + ((size_t)b * 8000 + e) * 4;
        float r0 = (cb[0] - dx) / scale;
        float r1 = (cb[1] - dy) / scale;
        float r2 = (cb[2] - dx) / scale;
        float r3 = (cb[3] - dy) / scale;

        size_t row = (size_t)b * TK + tid;
        float* dp = out + row * 5;
        dp[0] = valid ? r0 : 0.0f;
        dp[1] = valid ? r1 : 0.0f;
        dp[2] = valid ? r2 : 0.0f;
        dp[3] = valid ? r3 : 0.0f;
        dp[4] = valid ? v  : 0.0f;
        out[(size_t)BATCH * TK * 5 + row] = valid ? (float)(e / TK + 1) : 0.0f;  // cls
        out[(size_t)BATCH * TK * 6 + row] = valid ? 1.0f : 0.0f;                 // valid
    }
}

extern "C" void kernel_launch(void* const* d_in, const int* in_sizes, int n_in,
                              void* d_out, int out_size, void* d_ws, size_t ws_size,
                              hipStream_t stream) {
    const float* f0  = (const float*)d_in[0];
    const float* f1  = (const float*)d_in[1];
    const float* f2  = (const float*)d_in[2];
    const float* anc = (const float*)d_in[3];
    const float* ish = (const float*)d_in[4];
    const float* ori = (const float*)d_in[5];
    float* out = (float*)d_out;

    char* ws = (char*)d_ws;
    unsigned long long* cand  = (unsigned long long*)(ws + OFF_CAND);
    float*              boxes = (float*)(ws + OFF_BOXES);
    float*              cscr  = (float*)(ws + OFF_CSCORE);
    float*              cbox  = (float*)(ws + OFF_CBOX);
    unsigned long long* stage = (unsigned long long*)(ws + OFF_STAGE);
    unsigned*           cnt   = (unsigned*)(ws + OFF_CNT);

    hipMemsetAsync(cnt, 0, BATCH * NC * sizeof(unsigned), stream);

    // boxes: one thread per (b, cell)
    {
        int nThreads = BATCH * CELLS;
        int nBlocks = (nThreads + 255) / 256;
        box_kernel<<<nBlocks, 256, 0, stream>>>(f0, f1, f2, anc, ish, boxes);
    }

    // scores: one thread per (b, anchor, class, padded cell)
    {
        long long nThreads = (long long)BATCH * 3 * NC * PCELLS;
        int nBlocks = (int)((nThreads + 255) / 256);
        score_kernel<<<nBlocks, 256, 0, stream>>>(f0, f1, f2, cnt, cand);
    }

    nms_kernel<<<BATCH * NC, 512, 0, stream>>>(cnt, cand, boxes, cscr, cbox);

    topk1_kernel<<<BATCH * 10, 256, 0, stream>>>(cscr, stage);

    topk2_kernel<<<BATCH, 256, 0, stream>>>(stage, cbox, ish, ori, out);
}

// Round 7
// 331.787 us; speedup vs baseline: 3.5893x; 2.4048x over previous
//
#include <hip/hip_runtime.h>
#include <hip/hip_bf16.h>

// ---------------------------------------------------------------------------
// YOLOv3 post-processing for MI355X.
// Inputs (fp32): feats0 [8,255,19,19], feats1 [8,255,38,38], feats2 [8,255,76,76],
//                anchors [9,2], image_shape [2], ori_shape [8,2]
// Output (flat fp32): dets [8,100,5] ++ det_cls [8,100] ++ det_valid [8,100]
// ---------------------------------------------------------------------------

#define BATCH 8
#define NC 80
#define G0 19
#define G1 38
#define G2 76
#define C0 (G0*G0)          // 361
#define C1 (G1*G1)          // 1444
#define C2 (G2*G2)          // 5776
#define CELLS (C0+C1+C2)    // 7581
#define PCELLS 7616         // CELLS padded to multiple of 64
#define OFF_L0 0
#define OFF_L1 (C0*3)       // 1083
#define OFF_L2 (OFF_L1 + C1*3) // 5415
#define NBOX (CELLS*3)      // 22743
#define TK 100
#define SCORE_TH 0.5f
#define NMS_TH 0.3f

// score kernel decomposition
#define CPG 10              // classes per thread
#define NCG (NC/CPG)        // 8 class groups
#define SBLK 448            // 7 waves
#define CHUNKS (PCELLS/SBLK) // 17
#define SUBS 8              // sub-counters per (b,c)
#define CAPS 512            // capacity per sub-list
#define CAP (SUBS*CAPS)     // 4096 total per (b,c)

// workspace layout (bytes)
#define OFF_CAND   ((size_t)0)                                  // u64[640*8*512] = 20,971,520
#define OFF_BOXES  ((size_t)20971520)                           // f32[8*NBOX*4]  =  2,911,104
#define OFF_CSCORE ((size_t)23882624)                           // f32[8*8000]    =    256,000
#define OFF_CBOX   ((size_t)24138624)                           // f32[8*8000*4]  =  1,024,000
#define OFF_STAGE  ((size_t)25162624)                           // u64[8*1000]    =     64,000
#define OFF_CNT    ((size_t)25226624)                           // u32[640*8]     =     20,480

__device__ __forceinline__ float sigmoidf_(float x) {
    return 1.0f / (1.0f + expf(-x));
}

// descending bitonic sort of M (pow2) u64 keys in LDS
__device__ __forceinline__ void bitonic_desc(unsigned long long* s, unsigned M,
                                             unsigned tid, unsigned nthr) {
    for (unsigned k = 2; k <= M; k <<= 1) {
        for (unsigned j = k >> 1; j > 0; j >>= 1) {
            for (unsigned t = tid; t < M; t += nthr) {
                unsigned p = t ^ j;
                if (p > t) {
                    unsigned long long a = s[t], b = s[p];
                    bool desc = ((t & k) == 0);
                    if (desc ? (a < b) : (a > b)) { s[t] = b; s[p] = a; }
                }
            }
            __syncthreads();
        }
    }
}

__device__ __forceinline__ void cell_decomp(int cell, int& g, int& cl, int& off, int& layer) {
    if (cell < C0)            { layer = 0; g = G0; cl = cell;            off = OFF_L0; }
    else if (cell < C0 + C1)  { layer = 1; g = G1; cl = cell - C0;       off = OFF_L1; }
    else                      { layer = 2; g = G2; cl = cell - C0 - C1;  off = OFF_L2; }
}

// ---------------------------------------------------------------------------
// Kernel A: decode boxes. one thread per (image, cell, anchor).
// ---------------------------------------------------------------------------
__global__ __launch_bounds__(256) void box_kernel(
        const float* __restrict__ f0, const float* __restrict__ f1,
        const float* __restrict__ f2, const float* __restrict__ anchors,
        const float* __restrict__ image_shape,
        float* __restrict__ boxes) {
    int t = blockIdx.x * blockDim.x + threadIdx.x;
    if (t >= BATCH * NBOX) return;
    int b = t / NBOX;
    int r = t - b * NBOX;       // == gidx
    int a = r % 3;
    int cell = r / 3;

    int layer, g, cl, off;
    cell_decomp(cell, g, cl, off, layer);
    const float* f;
    if (layer == 0)      f = f0 + (size_t)b * 255 * C0;
    else if (layer == 1) f = f1 + (size_t)b * 255 * C1;
    else                 f = f2 + (size_t)b * 255 * C2;
    int S = g * g;
    int y = cl / g;
    int x = cl - y * g;

    const float in0 = (float)(G0 * 32);   // 608
    const float in1 = (float)(G0 * 32);
    float img0 = image_shape[0], img1 = image_shape[1];
    float mr   = fminf(in0 / img0, in1 / img1);
    float new0 = rintf(img0 * mr), new1 = rintf(img1 * mr);
    float ofs0 = (in0 - new0) * 0.5f / in0;
    float ofs1 = (in1 - new1) * 0.5f / in1;
    float scl0 = in0 / new0, scl1 = in1 / new1;

    const float* fa = f + (size_t)(a * 85) * S + cl;
    float tx = fa[0];
    float ty = fa[(size_t)S];
    float tw = fa[(size_t)2 * S];
    float th = fa[(size_t)3 * S];

    int am = (2 - layer) * 3 + a;            // ANCHOR_MASK
    float aw = anchors[am * 2 + 0];
    float ah = anchors[am * 2 + 1];

    float bx = (sigmoidf_(tx) + (float)x) / (float)g;
    float by = (sigmoidf_(ty) + (float)y) / (float)g;
    float bw = expf(tw) * aw / in0;
    float bh = expf(th) * ah / in1;

    float yy = (by - ofs0) * scl0;
    float xx = (bx - ofs1) * scl1;
    float hh = bh * scl0;
    float ww = bw * scl1;

    float4 bb;
    bb.x = (yy - hh * 0.5f) * img0;   // ymin
    bb.y = (xx - ww * 0.5f) * img1;   // xmin
    bb.z = (yy + hh * 0.5f) * img0;   // ymax
    bb.w = (xx + ww * 0.5f) * img1;   // xmax

    *(float4*)(boxes + ((size_t)b * NBOX + r) * 4) = bb;
}

// ---------------------------------------------------------------------------
// Kernel B: scores + scatter. grid = (CHUNKS, BATCH*3*NCG), block = 448.
// Each thread: one cell, CPG classes -> 10 independent ballot/atomic chains.
// 8-way sub-counters cut same-address atomic serialization.
// ---------------------------------------------------------------------------
__global__ __launch_bounds__(SBLK) void score_kernel(
        const float* __restrict__ f0, const float* __restrict__ f1,
        const float* __restrict__ f2,
        unsigned* __restrict__ cnt,
        unsigned long long* __restrict__ cand) {
    int chunk = blockIdx.x;
    int pg = blockIdx.y;                 // (b, a, cgrp)
    int cgrp = pg % NCG;
    int a    = (pg / NCG) % 3;
    int b    = pg / (NCG * 3);

    int cellp = chunk * SBLK + threadIdx.x;
    int sub = (chunk * 7 + (threadIdx.x >> 6)) & (SUBS - 1);   // wave-uniform
    bool vc = (cellp < CELLS);
    int cell = vc ? cellp : 0;

    int layer, g, cl, off;
    cell_decomp(cell, g, cl, off, layer);
    const float* f;
    if (layer == 0)      f = f0 + (size_t)b * 255 * C0;
    else if (layer == 1) f = f1 + (size_t)b * 255 * C1;
    else                 f = f2 + (size_t)b * 255 * C2;
    int S = g * g;
    const float* fa = f + (size_t)(a * 85) * S + cl;

    float tc = vc ? fa[(size_t)4 * S] : -1e30f;
    float conf = sigmoidf_(tc);
    int gidx = off + cl * 3 + a;
    int lane = threadIdx.x & 63;

    // load all CPG class logits (independent)
    float pl[CPG];
    #pragma unroll
    for (int k = 0; k < CPG; ++k) {
        int c = cgrp * CPG + k;
        pl[k] = vc ? fa[(size_t)(5 + c) * S] : -1e30f;
    }

    float sc[CPG];
    bool pred[CPG];
    #pragma unroll
    for (int k = 0; k < CPG; ++k) {
        sc[k] = conf * sigmoidf_(pl[k]);
        pred[k] = vc && (sc[k] >= SCORE_TH);
    }

    #pragma unroll
    for (int k = 0; k < CPG; ++k) {
        unsigned long long m = __ballot(pred[k]);
        if (m) {
            int c = cgrp * CPG + k;
            int idx = (b * NC + c) * SUBS + sub;       // wave-uniform
            int leader = __ffsll((long long)m) - 1;
            unsigned base = 0;
            if (lane == leader) base = atomicAdd(&cnt[idx], (unsigned)__popcll(m));
            base = (unsigned)__shfl((int)base, leader);
            if (pred[k]) {
                unsigned rank = (unsigned)__popcll(m & ((1ULL << lane) - 1ULL));
                unsigned slot = base + rank;
                if (slot < CAPS) {
                    unsigned long long key =
                        ((unsigned long long)__float_as_uint(sc[k]) << 32) |
                        (unsigned)(~(unsigned)gidx);
                    cand[(size_t)idx * CAPS + slot] = key;
                }
            }
        }
    }
}

// ---------------------------------------------------------------------------
// Kernel 2: per-(image,class) gather 8 sub-lists, sort desc, top-100, NMS
// ---------------------------------------------------------------------------
__global__ __launch_bounds__(512) void nms_kernel(
        const unsigned* __restrict__ cnt,
        const unsigned long long* __restrict__ cand,
        const float* __restrict__ boxes,
        float* __restrict__ cscore, float* __restrict__ cbox) {
    __shared__ unsigned long long s[CAP];
    __shared__ float bx[TK][4];
    __shared__ float sc[TK];
    __shared__ int keep[TK];

    int bc = blockIdx.x;
    int b = bc / NC;
    unsigned tid = threadIdx.x;

    unsigned nI[SUBS];
    unsigned pref[SUBS + 1];
    pref[0] = 0;
    #pragma unroll
    for (int i = 0; i < SUBS; ++i) {
        unsigned v = cnt[bc * SUBS + i];
        nI[i] = v > CAPS ? CAPS : v;
        pref[i + 1] = pref[i] + nI[i];
    }
    unsigned n = pref[SUBS];
    unsigned M = 128;
    while (M < n) M <<= 1;

    for (unsigned t = tid; t < M; t += 512) s[t] = 0ULL;
    __syncthreads();
    #pragma unroll
    for (int i = 0; i < SUBS; ++i) {
        const unsigned long long* cp = cand + (size_t)(bc * SUBS + i) * CAPS;
        for (unsigned t = tid; t < nI[i]; t += 512) s[pref[i] + t] = cp[t];
    }
    __syncthreads();

    bitonic_desc(s, M, tid, 512);

    int nv = (int)n < TK ? (int)n : TK;
    if (tid < TK) {
        if ((int)tid < nv) {
            unsigned long long key = s[tid];
            sc[tid] = __uint_as_float((unsigned)(key >> 32));
            unsigned gidx = ~(unsigned)(key & 0xFFFFFFFFu);
            const float* bp = boxes + ((size_t)b * NBOX + gidx) * 4;
            bx[tid][0] = bp[0]; bx[tid][1] = bp[1];
            bx[tid][2] = bp[2]; bx[tid][3] = bp[3];
            keep[tid] = 1;
        } else {
            sc[tid] = -1.0f;
            bx[tid][0] = bx[tid][1] = bx[tid][2] = bx[tid][3] = 0.0f;
            keep[tid] = 0;
        }
    }
    __syncthreads();

    for (int i = 0; i < nv - 1; ++i) {
        bool ki = (keep[i] != 0);
        if (ki && (int)tid > i && (int)tid < nv && keep[tid]) {
            float a0 = bx[i][0], a1 = bx[i][1], a2 = bx[i][2], a3 = bx[i][3];
            float c0 = bx[tid][0], c1 = bx[tid][1], c2 = bx[tid][2], c3 = bx[tid][3];
            float areaA = fmaxf(a2 - a0, 0.0f) * fmaxf(a3 - a1, 0.0f);
            float areaC = fmaxf(c2 - c0, 0.0f) * fmaxf(c3 - c1, 0.0f);
            float tl0 = fmaxf(a0, c0), tl1 = fmaxf(a1, c1);
            float br0 = fminf(a2, c2), br1 = fminf(a3, c3);
            float w = fmaxf(br0 - tl0, 0.0f), h = fmaxf(br1 - tl1, 0.0f);
            float inter = w * h;
            float iou = inter / (areaA + areaC - inter + 1e-9f);
            if (iou > NMS_TH) keep[tid] = 0;
        }
        __syncthreads();
    }

    if (tid < TK) {
        int c = bc - b * NC;
        size_t o = (size_t)b * 8000 + (size_t)c * TK + tid;
        bool k = (keep[tid] != 0);
        cscore[o] = k ? sc[tid] : -1.0f;
        float* cb = cbox + o * 4;
        cb[0] = bx[tid][0]; cb[1] = bx[tid][1];
        cb[2] = bx[tid][2]; cb[3] = bx[tid][3];
    }
}

// flip fp32 bits to a totally ordered unsigned (handles negatives)
__device__ __forceinline__ unsigned fflip(float v) {
    unsigned u = __float_as_uint(v);
    return (u & 0x80000000u) ? ~u : (u | 0x80000000u);
}
__device__ __forceinline__ float funflip(unsigned u) {
    return __uint_as_float((u & 0x80000000u) ? (u & 0x7FFFFFFFu) : ~u);
}

// ---------------------------------------------------------------------------
// Kernel 3a: per (image, chunk of 8 classes = 800 entries) -> top-100 keys
// ---------------------------------------------------------------------------
__global__ __launch_bounds__(256) void topk1_kernel(
        const float* __restrict__ cscore, unsigned long long* __restrict__ stage) {
    __shared__ unsigned long long s[1024];
    int blk = blockIdx.x;               // 0..79
    int b = blk / 10;
    int g = blk - b * 10;
    unsigned tid = threadIdx.x;
    for (unsigned t = tid; t < 1024; t += 256) {
        unsigned long long key = 0ULL;
        if (t < 800) {
            unsigned e = (unsigned)(g * 800 + t);
            float v = cscore[(size_t)b * 8000 + e];
            key = ((unsigned long long)fflip(v) << 32) | (unsigned)(~e);
        }
        s[t] = key;
    }
    __syncthreads();
    bitonic_desc(s, 1024, tid, 256);
    if (tid < TK) stage[(size_t)b * 1000 + (size_t)g * TK + tid] = s[tid];
}

// ---------------------------------------------------------------------------
// Kernel 3b: per image -> top-100 of 1000 staged keys, rescale, write output
// ---------------------------------------------------------------------------
__global__ __launch_bounds__(256) void topk2_kernel(
        const unsigned long long* __restrict__ stage,
        const float* __restrict__ cbox,
        const float* __restrict__ image_shape,
        const float* __restrict__ ori,
        float* __restrict__ out) {
    __shared__ unsigned long long s[1024];
    int b = blockIdx.x;
    unsigned tid = threadIdx.x;
    for (unsigned t = tid; t < 1024; t += 256)
        s[t] = (t < 1000) ? stage[(size_t)b * 1000 + t] : 0ULL;
    __syncthreads();
    bitonic_desc(s, 1024, tid, 256);

    if (tid < TK) {
        unsigned long long key = s[tid];
        float v = funflip((unsigned)(key >> 32));
        unsigned e = ~(unsigned)(key & 0xFFFFFFFFu);
        bool valid = (v >= SCORE_TH);

        float w = image_shape[0], h = image_shape[1];
        float iw = ori[b * 2 + 0], ih = ori[b * 2 + 1];
        float scale = fminf(w / iw, h / ih);
        float nw = floorf(iw * scale), nh = floorf(ih * scale);
        float dx = floorf((w - nw) * 0.5f), dy = floorf((h - nh) * 0.5f);

        const float* cb = cbox + ((size_t)b * 8000 + e) * 4;
        float r0 = (cb[0] - dx) / scale;
        float r1 = (cb[1] - dy) / scale;
        float r2 = (cb[2] - dx) / scale;
        float r3 = (cb[3] - dy) / scale;

        size_t row = (size_t)b * TK + tid;
        float* dp = out + row * 5;
        dp[0] = valid ? r0 : 0.0f;
        dp[1] = valid ? r1 : 0.0f;
        dp[2] = valid ? r2 : 0.0f;
        dp[3] = valid ? r3 : 0.0f;
        dp[4] = valid ? v  : 0.0f;
        out[(size_t)BATCH * TK * 5 + row] = valid ? (float)(e / TK + 1) : 0.0f;  // cls
        out[(size_t)BATCH * TK * 6 + row] = valid ? 1.0f : 0.0f;                 // valid
    }
}

extern "C" void kernel_launch(void* const* d_in, const int* in_sizes, int n_in,
                              void* d_out, int out_size, void* d_ws, size_t ws_size,
                              hipStream_t stream) {
    const float* f0  = (const float*)d_in[0];
    const float* f1  = (const float*)d_in[1];
    const float* f2  = (const float*)d_in[2];
    const float* anc = (const float*)d_in[3];
    const float* ish = (const float*)d_in[4];
    const float* ori = (const float*)d_in[5];
    float* out = (float*)d_out;

    char* ws = (char*)d_ws;
    unsigned long long* cand  = (unsigned long long*)(ws + OFF_CAND);
    float*              boxes = (float*)(ws + OFF_BOXES);
    float*              cscr  = (float*)(ws + OFF_CSCORE);
    float*              cbox  = (float*)(ws + OFF_CBOX);
    unsigned long long* stage = (unsigned long long*)(ws + OFF_STAGE);
    unsigned*           cnt   = (unsigned*)(ws + OFF_CNT);

    hipMemsetAsync(cnt, 0, BATCH * NC * SUBS * sizeof(unsigned), stream);

    // boxes: one thread per (b, cell, anchor)
    {
        int nThreads = BATCH * NBOX;
        int nBlocks = (nThreads + 255) / 256;
        box_kernel<<<nBlocks, 256, 0, stream>>>(f0, f1, f2, anc, ish, boxes);
    }

    // scores
    {
        dim3 grid(CHUNKS, BATCH * 3 * NCG);
        score_kernel<<<grid, SBLK, 0, stream>>>(f0, f1, f2, cnt, cand);
    }

    nms_kernel<<<BATCH * NC, 512, 0, stream>>>(cnt, cand, boxes, cscr, cbox);

    topk1_kernel<<<BATCH * 10, 256, 0, stream>>>(cscr, stage);

    topk2_kernel<<<BATCH, 256, 0, stream>>>(stage, cbox, ish, ori, out);
}

// Round 12
// 288.218 us; speedup vs baseline: 4.1319x; 1.1512x over previous
//
#include <hip/hip_runtime.h>
#include <hip/hip_bf16.h>

// ---------------------------------------------------------------------------
// YOLOv3 post-processing for MI355X.
// Inputs (fp32): feats0 [8,255,19,19], feats1 [8,255,38,38], feats2 [8,255,76,76],
//                anchors [9,2], image_shape [2], ori_shape [8,2]
// Output (flat fp32): dets [8,100,5] ++ det_cls [8,100] ++ det_valid [8,100]
// ---------------------------------------------------------------------------

#define BATCH 8
#define NC 80
#define G0 19
#define G1 38
#define G2 76
#define C0 (G0*G0)          // 361
#define C1 (G1*G1)          // 1444
#define C2 (G2*G2)          // 5776
#define CELLS (C0+C1+C2)    // 7581
#define PCELLS 7616         // CELLS padded to multiple of 64
#define OFF_L0 0
#define OFF_L1 (C0*3)       // 1083
#define OFF_L2 (OFF_L1 + C1*3) // 5415
#define NBOX (CELLS*3)      // 22743
#define TK 100
#define SCORE_TH 0.5f
#define NMS_TH 0.3f

// score kernel decomposition
#define CPG 10              // classes per thread
#define NCG (NC/CPG)        // 8 class groups
#define SBLK 448            // 7 waves
#define CHUNKS (PCELLS/SBLK) // 17
#define SUBS 8              // sub-counters per (b,c)
#define CAPS 512            // capacity per sub-list
#define CAP (SUBS*CAPS)     // 4096 total per (b,c)

// workspace layout (bytes)
#define OFF_CAND   ((size_t)0)                                  // u64[640*8*512] = 20,971,520
#define OFF_BOXES  ((size_t)20971520)                           // f32[8*NBOX*4]  =  2,911,104
#define OFF_CSCORE ((size_t)23882624)                           // f32[8*8000]    =    256,000
#define OFF_CBOX   ((size_t)24138624)                           // f32[8*8000*4]  =  1,024,000
#define OFF_STAGE  ((size_t)25162624)                           // u64[8*1000]    =     64,000
#define OFF_CNT    ((size_t)25226624)                           // u32[640*8]     =     20,480

__device__ __forceinline__ float sigmoidf_(float x) {
    return 1.0f / (1.0f + expf(-x));
}

// descending bitonic sort of M (pow2) u64 keys in LDS (used by topk kernels)
__device__ __forceinline__ void bitonic_desc(unsigned long long* s, unsigned M,
                                             unsigned tid, unsigned nthr) {
    for (unsigned k = 2; k <= M; k <<= 1) {
        for (unsigned j = k >> 1; j > 0; j >>= 1) {
            for (unsigned t = tid; t < M; t += nthr) {
                unsigned p = t ^ j;
                if (p > t) {
                    unsigned long long a = s[t], b = s[p];
                    bool desc = ((t & k) == 0);
                    if (desc ? (a < b) : (a > b)) { s[t] = b; s[p] = a; }
                }
            }
            __syncthreads();
        }
    }
}

__device__ __forceinline__ void cell_decomp(int cell, int& g, int& cl, int& off, int& layer) {
    if (cell < C0)            { layer = 0; g = G0; cl = cell;            off = OFF_L0; }
    else if (cell < C0 + C1)  { layer = 1; g = G1; cl = cell - C0;       off = OFF_L1; }
    else                      { layer = 2; g = G2; cl = cell - C0 - C1;  off = OFF_L2; }
}

// ---- wave-local u64 helpers ------------------------------------------------
__device__ __forceinline__ unsigned long long maxu(unsigned long long a, unsigned long long b) { return a > b ? a : b; }
__device__ __forceinline__ unsigned long long minu(unsigned long long a, unsigned long long b) { return a < b ? a : b; }

__device__ __forceinline__ unsigned long long ux64(unsigned long long v, int m) {
    int lo = __shfl_xor((int)(unsigned)v, m, 64);
    int hi = __shfl_xor((int)(unsigned)(v >> 32), m, 64);
    return ((unsigned long long)(unsigned)hi << 32) | (unsigned)lo;
}

// in-register bitonic sort of 128 u64 keys held by one wave (2/lane), desc.
// element index e = slot*64 + lane.
__device__ __forceinline__ void wsort128(unsigned long long& v0, unsigned long long& v1, int lane) {
    #pragma unroll
    for (int k = 2; k <= 32; k <<= 1) {
        #pragma unroll
        for (int j = k >> 1; j >= 1; j >>= 1) {
            bool desc = ((lane & k) == 0);
            bool lower = ((lane & j) == 0);
            bool km = (lower == desc);
            unsigned long long p0 = ux64(v0, j); v0 = km ? maxu(v0, p0) : minu(v0, p0);
            unsigned long long p1 = ux64(v1, j); v1 = km ? maxu(v1, p1) : minu(v1, p1);
        }
    }
    // k = 64 phase: slot0 desc, slot1 asc
    #pragma unroll
    for (int j = 32; j >= 1; j >>= 1) {
        bool lower = ((lane & j) == 0);
        unsigned long long p0 = ux64(v0, j); v0 = lower ? maxu(v0, p0) : minu(v0, p0);
        unsigned long long p1 = ux64(v1, j); v1 = lower ? minu(v1, p1) : maxu(v1, p1);
    }
    // k = 128 phase: j=64 (slot swap) then j=32..1, all desc
    { unsigned long long t0 = maxu(v0, v1), t1 = minu(v0, v1); v0 = t0; v1 = t1; }
    #pragma unroll
    for (int j = 32; j >= 1; j >>= 1) {
        bool lower = ((lane & j) == 0);
        unsigned long long p0 = ux64(v0, j); v0 = lower ? maxu(v0, p0) : minu(v0, p0);
        unsigned long long p1 = ux64(v1, j); v1 = lower ? maxu(v1, p1) : minu(v1, p1);
    }
}

// A (a0,a1) and B (b0,b1) each sorted desc; result: top-128 of A∪B sorted desc in (a0,a1).
// C[i]=max(A[i],B[127-i]) is the lower half of the first bitonic-merge exchange
// of the 256-seq [A, reverse(B)] -> contains exactly the top-128, and is bitonic.
__device__ __forceinline__ void wmergetop(unsigned long long& a0, unsigned long long& a1,
                                          unsigned long long b0, unsigned long long b1, int lane) {
    unsigned long long r0 = ux64(b1, 63);   // B[127-(0*64+lane)]
    unsigned long long r1 = ux64(b0, 63);   // B[127-(64+lane)]
    a0 = maxu(a0, r0); a1 = maxu(a1, r1);
    { unsigned long long t0 = maxu(a0, a1), t1 = minu(a0, a1); a0 = t0; a1 = t1; }
    #pragma unroll
    for (int j = 32; j >= 1; j >>= 1) {
        bool lower = ((lane & j) == 0);
        unsigned long long p0 = ux64(a0, j); a0 = lower ? maxu(a0, p0) : minu(a0, p0);
        unsigned long long p1 = ux64(a1, j); a1 = lower ? maxu(a1, p1) : minu(a1, p1);
    }
}

// ---------------------------------------------------------------------------
// Kernel A: decode boxes. one thread per (image, cell, anchor).
// ---------------------------------------------------------------------------
__global__ __launch_bounds__(256) void box_kernel(
        const float* __restrict__ f0, const float* __restrict__ f1,
        const float* __restrict__ f2, const float* __restrict__ anchors,
        const float* __restrict__ image_shape,
        float* __restrict__ boxes) {
    int t = blockIdx.x * blockDim.x + threadIdx.x;
    if (t >= BATCH * NBOX) return;
    int b = t / NBOX;
    int r = t - b * NBOX;       // == gidx
    int a = r % 3;
    int cell = r / 3;

    int layer, g, cl, off;
    cell_decomp(cell, g, cl, off, layer);
    const float* f;
    if (layer == 0)      f = f0 + (size_t)b * 255 * C0;
    else if (layer == 1) f = f1 + (size_t)b * 255 * C1;
    else                 f = f2 + (size_t)b * 255 * C2;
    int S = g * g;
    int y = cl / g;
    int x = cl - y * g;

    const float in0 = (float)(G0 * 32);   // 608
    const float in1 = (float)(G0 * 32);
    float img0 = image_shape[0], img1 = image_shape[1];
    float mr   = fminf(in0 / img0, in1 / img1);
    float new0 = rintf(img0 * mr), new1 = rintf(img1 * mr);
    float ofs0 = (in0 - new0) * 0.5f / in0;
    float ofs1 = (in1 - new1) * 0.5f / in1;
    float scl0 = in0 / new0, scl1 = in1 / new1;

    const float* fa = f + (size_t)(a * 85) * S + cl;
    float tx = fa[0];
    float ty = fa[(size_t)S];
    float tw = fa[(size_t)2 * S];
    float th = fa[(size_t)3 * S];

    int am = (2 - layer) * 3 + a;            // ANCHOR_MASK
    float aw = anchors[am * 2 + 0];
    float ah = anchors[am * 2 + 1];

    float bx = (sigmoidf_(tx) + (float)x) / (float)g;
    float by = (sigmoidf_(ty) + (float)y) / (float)g;
    float bw = expf(tw) * aw / in0;
    float bh = expf(th) * ah / in1;

    float yy = (by - ofs0) * scl0;
    float xx = (bx - ofs1) * scl1;
    float hh = bh * scl0;
    float ww = bw * scl1;

    float4 bb;
    bb.x = (yy - hh * 0.5f) * img0;   // ymin
    bb.y = (xx - ww * 0.5f) * img1;   // xmin
    bb.z = (yy + hh * 0.5f) * img0;   // ymax
    bb.w = (xx + ww * 0.5f) * img1;   // xmax

    *(float4*)(boxes + ((size_t)b * NBOX + r) * 4) = bb;
}

// ---------------------------------------------------------------------------
// Kernel B: scores + scatter. grid = (CHUNKS, BATCH*3*NCG), block = 448.
// ---------------------------------------------------------------------------
__global__ __launch_bounds__(SBLK) void score_kernel(
        const float* __restrict__ f0, const float* __restrict__ f1,
        const float* __restrict__ f2,
        unsigned* __restrict__ cnt,
        unsigned long long* __restrict__ cand) {
    int chunk = blockIdx.x;
    int pg = blockIdx.y;                 // (b, a, cgrp)
    int cgrp = pg % NCG;
    int a    = (pg / NCG) % 3;
    int b    = pg / (NCG * 3);

    int cellp = chunk * SBLK + threadIdx.x;
    int sub = (chunk * 7 + (threadIdx.x >> 6)) & (SUBS - 1);   // wave-uniform
    bool vc = (cellp < CELLS);
    int cell = vc ? cellp : 0;

    int layer, g, cl, off;
    cell_decomp(cell, g, cl, off, layer);
    const float* f;
    if (layer == 0)      f = f0 + (size_t)b * 255 * C0;
    else if (layer == 1) f = f1 + (size_t)b * 255 * C1;
    else                 f = f2 + (size_t)b * 255 * C2;
    int S = g * g;
    const float* fa = f + (size_t)(a * 85) * S + cl;

    float tc = vc ? fa[(size_t)4 * S] : -1e30f;
    float conf = sigmoidf_(tc);
    int gidx = off + cl * 3 + a;
    int lane = threadIdx.x & 63;

    float pl[CPG];
    #pragma unroll
    for (int k = 0; k < CPG; ++k) {
        int c = cgrp * CPG + k;
        pl[k] = vc ? fa[(size_t)(5 + c) * S] : -1e30f;
    }

    float sc[CPG];
    bool pred[CPG];
    #pragma unroll
    for (int k = 0; k < CPG; ++k) {
        sc[k] = conf * sigmoidf_(pl[k]);
        pred[k] = vc && (sc[k] >= SCORE_TH);
    }

    #pragma unroll
    for (int k = 0; k < CPG; ++k) {
        unsigned long long m = __ballot(pred[k]);
        if (m) {
            int c = cgrp * CPG + k;
            int idx = (b * NC + c) * SUBS + sub;       // wave-uniform
            int leader = __ffsll((long long)m) - 1;
            unsigned base = 0;
            if (lane == leader) base = atomicAdd(&cnt[idx], (unsigned)__popcll(m));
            base = (unsigned)__shfl((int)base, leader);
            if (pred[k]) {
                unsigned rank = (unsigned)__popcll(m & ((1ULL << lane) - 1ULL));
                unsigned slot = base + rank;
                if (slot < CAPS) {
                    unsigned long long key =
                        ((unsigned long long)__float_as_uint(sc[k]) << 32) |
                        (unsigned)(~(unsigned)gidx);
                    cand[(size_t)idx * CAPS + slot] = key;
                }
            }
        }
    }
}

// ---------------------------------------------------------------------------
// Kernel 2: per-(image,class) exact top-128 via wave-register bitonic chunks
// + barrier-free single-wave NMS. One block of 256 threads (4 waves) per (b,c).
// ---------------------------------------------------------------------------
__global__ __launch_bounds__(256) void nms_kernel(
        const unsigned* __restrict__ cnt,
        const unsigned long long* __restrict__ cand,
        const float* __restrict__ boxes,
        float* __restrict__ cscore, float* __restrict__ cbox) {
    __shared__ unsigned long long s[SUBS * CAPS];   // 4096 * 8B = 32 KB

    int bc = blockIdx.x;
    int b = bc / NC;
    int c = bc - b * NC;
    int tid = threadIdx.x;
    int lane = tid & 63;
    int wid = tid >> 6;

    unsigned pref[SUBS + 1];
    pref[0] = 0;
    #pragma unroll
    for (int i = 0; i < SUBS; ++i) {
        unsigned v = cnt[bc * SUBS + i];
        v = v > CAPS ? CAPS : v;
        pref[i + 1] = pref[i] + v;
    }
    unsigned n = pref[SUBS];
    int nchunks = (int)((n + 127u) >> 7);
    int P = 1;
    while (P < nchunks) P <<= 1;

    const unsigned long long* cbase = cand + (size_t)bc * (SUBS * CAPS);

    // phase 1: each wave register-sorts 128-chunks (desc), zero barriers inside
    for (int ch = wid; ch < P; ch += 4) {
        unsigned e0 = (unsigned)(ch * 128 + lane);
        unsigned e1 = e0 + 64;
        unsigned long long v0 = 0ULL, v1 = 0ULL;
        if (e0 < n) {
            unsigned adj = 0;
            #pragma unroll
            for (int q = 1; q < SUBS; ++q) if (e0 >= pref[q]) adj = (unsigned)(q * CAPS) - pref[q];
            v0 = cbase[e0 + adj];
        }
        if (e1 < n) {
            unsigned adj = 0;
            #pragma unroll
            for (int q = 1; q < SUBS; ++q) if (e1 >= pref[q]) adj = (unsigned)(q * CAPS) - pref[q];
            v1 = cbase[e1 + adj];
        }
        wsort128(v0, v1, lane);
        s[ch * 128 + lane] = v0;
        s[ch * 128 + 64 + lane] = v1;
    }
    __syncthreads();

    // phase 2: binary top-128 merge reduction, one barrier per round
    for (int S2 = P >> 1; S2 >= 1; S2 >>= 1) {
        for (int m = wid; m < S2; m += 4) {
            unsigned long long a0 = s[m * 128 + lane], a1 = s[m * 128 + 64 + lane];
            unsigned long long b0 = s[(m + S2) * 128 + lane], b1 = s[(m + S2) * 128 + 64 + lane];
            wmergetop(a0, a1, b0, b1, lane);
            s[m * 128 + lane] = a0;
            s[m * 128 + 64 + lane] = a1;
        }
        __syncthreads();
    }

    // phase 3: single-wave barrier-free NMS on sorted top-128 (chunk 0)
    if (wid == 0) {
        int nv = (int)n < TK ? (int)n : TK;
        unsigned long long k0 = s[lane], k1 = s[64 + lane];
        int e0 = lane, e1 = 64 + lane;
        bool val0 = e0 < nv, val1 = e1 < nv;
        float sc0 = __uint_as_float((unsigned)(k0 >> 32));
        float sc1 = __uint_as_float((unsigned)(k1 >> 32));
        unsigned g0 = ~(unsigned)(k0 & 0xFFFFFFFFu);
        unsigned g1 = ~(unsigned)(k1 & 0xFFFFFFFFu);
        float4 B0 = make_float4(0.f, 0.f, 0.f, 0.f);
        float4 B1 = make_float4(0.f, 0.f, 0.f, 0.f);
        if (val0) B0 = *(const float4*)(boxes + ((size_t)b * NBOX + g0) * 4);
        if (val1) B1 = *(const float4*)(boxes + ((size_t)b * NBOX + g1) * 4);
        unsigned keepw = (val0 ? 1u : 0u) | (val1 ? 2u : 0u);

        for (int i = 0; i + 1 < nv; ++i) {
            unsigned kw = (unsigned)__shfl((int)keepw, i & 63);
            if (!((kw >> (i >> 6)) & 1u)) continue;
            float ax = __shfl((i < 64) ? B0.x : B1.x, i & 63);
            float ay = __shfl((i < 64) ? B0.y : B1.y, i & 63);
            float az = __shfl((i < 64) ? B0.z : B1.z, i & 63);
            float aw = __shfl((i < 64) ? B0.w : B1.w, i & 63);
            float areaA = fmaxf(az - ax, 0.0f) * fmaxf(aw - ay, 0.0f);
            if ((keepw & 1u) && e0 > i) {
                float areaC = fmaxf(B0.z - B0.x, 0.0f) * fmaxf(B0.w - B0.y, 0.0f);
                float tl0 = fmaxf(ax, B0.x), tl1 = fmaxf(ay, B0.y);
                float br0 = fminf(az, B0.z), br1 = fminf(aw, B0.w);
                float w = fmaxf(br0 - tl0, 0.0f), h = fmaxf(br1 - tl1, 0.0f);
                float inter = w * h;
                float iou = inter / (areaA + areaC - inter + 1e-9f);
                if (iou > NMS_TH) keepw &= ~1u;
            }
            if ((keepw & 2u) && e1 > i) {
                float areaC = fmaxf(B1.z - B1.x, 0.0f) * fmaxf(B1.w - B1.y, 0.0f);
                float tl0 = fmaxf(ax, B1.x), tl1 = fmaxf(ay, B1.y);
                float br0 = fminf(az, B1.z), br1 = fminf(aw, B1.w);
                float w = fmaxf(br0 - tl0, 0.0f), h = fmaxf(br1 - tl1, 0.0f);
                float inter = w * h;
                float iou = inter / (areaA + areaC - inter + 1e-9f);
                if (iou > NMS_TH) keepw &= ~2u;
            }
        }

        size_t obase = (size_t)b * 8000 + (size_t)c * TK;
        if (e0 < TK) {
            cscore[obase + e0] = (keepw & 1u) ? sc0 : -1.0f;
            *(float4*)(cbox + (obase + e0) * 4) = B0;
        }
        if (e1 < TK) {
            cscore[obase + e1] = (keepw & 2u) ? sc1 : -1.0f;
            *(float4*)(cbox + (obase + e1) * 4) = B1;
        }
    }
}

// flip fp32 bits to a totally ordered unsigned (handles negatives)
__device__ __forceinline__ unsigned fflip(float v) {
    unsigned u = __float_as_uint(v);
    return (u & 0x80000000u) ? ~u : (u | 0x80000000u);
}
__device__ __forceinline__ float funflip(unsigned u) {
    return __uint_as_float((u & 0x80000000u) ? (u & 0x7FFFFFFFu) : ~u);
}

// ---------------------------------------------------------------------------
// Kernel 3a: per (image, chunk of 8 classes = 800 entries) -> top-100 keys
// ---------------------------------------------------------------------------
__global__ __launch_bounds__(256) void topk1_kernel(
        const float* __restrict__ cscore, unsigned long long* __restrict__ stage) {
    __shared__ unsigned long long s[1024];
    int blk = blockIdx.x;               // 0..79
    int b = blk / 10;
    int g = blk - b * 10;
    unsigned tid = threadIdx.x;
    for (unsigned t = tid; t < 1024; t += 256) {
        unsigned long long key = 0ULL;
        if (t < 800) {
            unsigned e = (unsigned)(g * 800 + t);
            float v = cscore[(size_t)b * 8000 + e];
            key = ((unsigned long long)fflip(v) << 32) | (unsigned)(~e);
        }
        s[t] = key;
    }
    __syncthreads();
    bitonic_desc(s, 1024, tid, 256);
    if (tid < TK) stage[(size_t)b * 1000 + (size_t)g * TK + tid] = s[tid];
}

// ---------------------------------------------------------------------------
// Kernel 3b: per image -> top-100 of 1000 staged keys, rescale, write output
// ---------------------------------------------------------------------------
__global__ __launch_bounds__(256) void topk2_kernel(
        const unsigned long long* __restrict__ stage,
        const float* __restrict__ cbox,
        const float* __restrict__ image_shape,
        const float* __restrict__ ori,
        float* __restrict__ out) {
    __shared__ unsigned long long s[1024];
    int b = blockIdx.x;
    unsigned tid = threadIdx.x;
    for (unsigned t = tid; t < 1024; t += 256)
        s[t] = (t < 1000) ? stage[(size_t)b * 1000 + t] : 0ULL;
    __syncthreads();
    bitonic_desc(s, 1024, tid, 256);

    if (tid < TK) {
        unsigned long long key = s[tid];
        float v = funflip((unsigned)(key >> 32));
        unsigned e = ~(unsigned)(key & 0xFFFFFFFFu);
        bool valid = (v >= SCORE_TH);

        float w = image_shape[0], h = image_shape[1];
        float iw = ori[b * 2 + 0], ih = ori[b * 2 + 1];
        float scale = fminf(w / iw, h / ih);
        float nw = floorf(iw * scale), nh = floorf(ih * scale);
        float dx = floorf((w - nw) * 0.5f), dy = floorf((h - nh) * 0.5f);

        const float* cb = cbox + ((size_t)b * 8000 + e) * 4;
        float r0 = (cb[0] - dx) / scale;
        float r1 = (cb[1] - dy) / scale;
        float r2 = (cb[2] - dx) / scale;
        float r3 = (cb[3] - dy) / scale;

        size_t row = (size_t)b * TK + tid;
        float* dp = out + row * 5;
        dp[0] = valid ? r0 : 0.0f;
        dp[1] = valid ? r1 : 0.0f;
        dp[2] = valid ? r2 : 0.0f;
        dp[3] = valid ? r3 : 0.0f;
        dp[4] = valid ? v  : 0.0f;
        out[(size_t)BATCH * TK * 5 + row] = valid ? (float)(e / TK + 1) : 0.0f;  // cls
        out[(size_t)BATCH * TK * 6 + row] = valid ? 1.0f : 0.0f;                 // valid
    }
}

extern "C" void kernel_launch(void* const* d_in, const int* in_sizes, int n_in,
                              void* d_out, int out_size, void* d_ws, size_t ws_size,
                              hipStream_t stream) {
    const float* f0  = (const float*)d_in[0];
    const float* f1  = (const float*)d_in[1];
    const float* f2  = (const float*)d_in[2];
    const float* anc = (const float*)d_in[3];
    const float* ish = (const float*)d_in[4];
    const float* ori = (const float*)d_in[5];
    float* out = (float*)d_out;

    char* ws = (char*)d_ws;
    unsigned long long* cand  = (unsigned long long*)(ws + OFF_CAND);
    float*              boxes = (float*)(ws + OFF_BOXES);
    float*              cscr  = (float*)(ws + OFF_CSCORE);
    float*              cbox  = (float*)(ws + OFF_CBOX);
    unsigned long long* stage = (unsigned long long*)(ws + OFF_STAGE);
    unsigned*           cnt   = (unsigned*)(ws + OFF_CNT);

    hipMemsetAsync(cnt, 0, BATCH * NC * SUBS * sizeof(unsigned), stream);

    // boxes: one thread per (b, cell, anchor)
    {
        int nThreads = BATCH * NBOX;
        int nBlocks = (nThreads + 255) / 256;
        box_kernel<<<nBlocks, 256, 0, stream>>>(f0, f1, f2, anc, ish, boxes);
    }

    // scores
    {
        dim3 grid(CHUNKS, BATCH * 3 * NCG);
        score_kernel<<<grid, SBLK, 0, stream>>>(f0, f1, f2, cnt, cand);
    }

    nms_kernel<<<BATCH * NC, 256, 0, stream>>>(cnt, cand, boxes, cscr, cbox);

    topk1_kernel<<<BATCH * 10, 256, 0, stream>>>(cscr, stage);

    topk2_kernel<<<BATCH, 256, 0, stream>>>(stage, cbox, ish, ori, out);
}